// Round 10
// baseline (317.188 us; speedup 1.0000x reference)
//
#include <hip/hip_runtime.h>

// GAT layer, N=8192, F_in=512, F_out=256.
// Pipeline: k_mask (adj -> 8MB bitmask via int4+ballot, j-permuted layout)
//   -> k_u -> k_rowvec (wh1, wh2' permuted, blockmax) -> k_wh (whT' bf16, permuted m)
//   -> k_attn (bitmask softmax-numerator x wh; split-K=8, 2 blocks/CU, 4 waves/SIMD)
//   -> k_out (combine 8 partials + elu)
// j-permutation pi(256T+4l+k) = 256T+64k+l applied to bm, wh2', whT' m-axis;
// softmax sum over j is permutation-invariant.

typedef __attribute__((ext_vector_type(8))) short short8;
typedef __attribute__((ext_vector_type(4))) float f32x4;

#define LOG2E 1.4426950408889634f

__device__ __forceinline__ unsigned short f2bf(float f) {
  unsigned int u = __float_as_uint(f);
  unsigned int r = u + 0x7FFFu + ((u >> 16) & 1u);  // RNE
  return (unsigned short)(r >> 16);
}

__device__ __forceinline__ int jperm(int j) {  // pi: (T)(l)(k) -> (T)(k)(l)
  return (j & ~255) | ((j & 3) << 6) | ((j >> 2) & 63);
}

// ------- adj -> bitmask (permuted): word[row][T*4+k] bit l = adj[row][256T+4l+k] -------
__global__ __launch_bounds__(256) void k_mask(const int* __restrict__ adj,
                                              unsigned long long* __restrict__ bm) {
  const int row = blockIdx.x * 4 + (threadIdx.x >> 6);  // grid 2048
  const int lane = threadIdx.x & 63;
  const int* ap = adj + (size_t)row * 8192 + lane * 4;
  unsigned long long* bp = bm + (size_t)row * 128;
#pragma unroll 4
  for (int T = 0; T < 32; T++) {
    int4 v = *(const int4*)(ap + T * 256);
    unsigned long long m0 = __ballot(v.x > 0);
    unsigned long long m1 = __ballot(v.y > 0);
    unsigned long long m2 = __ballot(v.z > 0);
    unsigned long long m3 = __ballot(v.w > 0);
    if (lane == 0) {
      *(ulonglong2*)(bp + T * 4) = make_ulonglong2(m0, m1);
      *(ulonglong2*)(bp + T * 4 + 2) = make_ulonglong2(m2, m3);
    }
  }
}

// ---------------- u1 = W^T a1, u2 = W^T a2 (512 each), atomic-free ----------------
__global__ __launch_bounds__(512) void k_u(const float* __restrict__ W,
                                           const float* __restrict__ a1,
                                           const float* __restrict__ a2,
                                           float* __restrict__ u1,
                                           float* __restrict__ u2) {
  __shared__ float p1[16][32], p2[16][32];
  const int tid = threadIdx.x;
  const int kk = tid & 31, og = tid >> 5;
  const int k0 = blockIdx.x * 32;  // grid 16
  float s1 = 0.f, s2 = 0.f;
#pragma unroll
  for (int j = 0; j < 16; j++) {
    const int o = og * 16 + j;
    const float w = W[(size_t)o * 512 + k0 + kk];
    s1 += w * a1[o];
    s2 += w * a2[o];
  }
  p1[og][kk] = s1;
  p2[og][kk] = s2;
  __syncthreads();
  if (tid < 32) {
    float t1 = 0.f, t2 = 0.f;
#pragma unroll
    for (int g = 0; g < 16; g++) { t1 += p1[g][tid]; t2 += p2[g][tid]; }
    u1[k0 + tid] = t1;
    u2[k0 + tid] = t2;
  }
}

// --- wh1[i] = h_i.u1*log2e; wh2'[pi(i)] = h_i.u2*log2e; per-block max ---
__global__ __launch_bounds__(256) void k_rowvec(const float* __restrict__ h,
                                                const float* __restrict__ u1,
                                                const float* __restrict__ u2,
                                                float* __restrict__ wh1,
                                                float* __restrict__ wh2,
                                                float* __restrict__ pmax) {
  __shared__ float su1[512], su2[512];
  __shared__ float smax[4];
  const int tid = threadIdx.x;
  for (int i = tid; i < 512; i += 256) { su1[i] = u1[i]; su2[i] = u2[i]; }
  __syncthreads();
  const int lane = tid & 63;
  const int row = blockIdx.x * 4 + (tid >> 6);  // grid 2048
  const float* hp = h + (size_t)row * 512 + lane * 8;
  float4 x0 = *(const float4*)hp;
  float4 x1 = *(const float4*)(hp + 4);
  const float* q1 = su1 + lane * 8;
  const float* q2 = su2 + lane * 8;
  float s1 = x0.x * q1[0] + x0.y * q1[1] + x0.z * q1[2] + x0.w * q1[3]
           + x1.x * q1[4] + x1.y * q1[5] + x1.z * q1[6] + x1.w * q1[7];
  float s2 = x0.x * q2[0] + x0.y * q2[1] + x0.z * q2[2] + x0.w * q2[3]
           + x1.x * q2[4] + x1.y * q2[5] + x1.z * q2[6] + x1.w * q2[7];
#pragma unroll
  for (int off = 32; off >= 1; off >>= 1) {
    s1 += __shfl_xor(s1, off);
    s2 += __shfl_xor(s2, off);
  }
  if (lane == 0) {
    wh1[row] = s1 * LOG2E;
    wh2[jperm(row)] = s2 * LOG2E;
    smax[tid >> 6] = s2 * LOG2E;
  }
  __syncthreads();
  if (tid == 0)
    pmax[blockIdx.x] = fmaxf(fmaxf(smax[0], smax[1]), fmaxf(smax[2], smax[3]));
}

// --- whT'[n][pi(m)] = (h @ W^T)[m][n] bf16; block 0 also reduces pmax -> gmax ---
__global__ __launch_bounds__(512, 1) void k_wh(const float* __restrict__ h,
                                               const float* __restrict__ W,
                                               unsigned short* __restrict__ whT,
                                               const float* __restrict__ pmax,
                                               float* __restrict__ gmax) {
  __shared__ uint4 lds[2560];
  __shared__ float sred[8];
  const int tid = threadIdx.x;
  if (blockIdx.x == 0) {  // fold k_max
    float m = -3.0e38f;
    for (int i = tid; i < 2048; i += 512) m = fmaxf(m, pmax[i]);
#pragma unroll
    for (int off = 32; off >= 1; off >>= 1) m = fmaxf(m, __shfl_xor(m, off));
    if ((tid & 63) == 0) sred[tid >> 6] = m;
    __syncthreads();
    if (tid == 0) {
      float g = sred[0];
#pragma unroll
      for (int i = 1; i < 8; i++) g = fmaxf(g, sred[i]);
      gmax[0] = g;
    }
  }
  const int i0 = blockIdx.x * 64;  // grid 128
  const int lane = tid & 63, wid = tid >> 6;
  const int wm = wid >> 2, wn = wid & 3;
  const int l16 = lane & 15, lq = lane >> 4;
  const int hr = tid >> 3, hc = tid & 7;
  const int wr = tid >> 1, wc = tid & 1;

  f32x4 acc[2][4] = {};

  for (int t = 0; t < 8; t++) {
    const int k0 = t * 64;
    const float* hp = h + (size_t)(i0 + hr) * 512 + k0 + hc * 8;
    float4 hx = *(const float4*)hp;
    float4 hy = *(const float4*)(hp + 4);
    const float* wp = W + (size_t)wr * 512 + k0 + wc * 32;
    float4 wv[8];
#pragma unroll
    for (int q = 0; q < 8; q++) wv[q] = *(const float4*)(wp + q * 4);

    __syncthreads();
    uint4 hw;
    hw.x = (unsigned)f2bf(hx.x) | ((unsigned)f2bf(hx.y) << 16);
    hw.y = (unsigned)f2bf(hx.z) | ((unsigned)f2bf(hx.w) << 16);
    hw.z = (unsigned)f2bf(hy.x) | ((unsigned)f2bf(hy.y) << 16);
    hw.w = (unsigned)f2bf(hy.z) | ((unsigned)f2bf(hy.w) << 16);
    lds[hr * 8 + (hc ^ (hr & 7))] = hw;
#pragma unroll
    for (int q = 0; q < 4; q++) {
      uint4 ww;
      ww.x = (unsigned)f2bf(wv[2 * q].x) | ((unsigned)f2bf(wv[2 * q].y) << 16);
      ww.y = (unsigned)f2bf(wv[2 * q].z) | ((unsigned)f2bf(wv[2 * q].w) << 16);
      ww.z = (unsigned)f2bf(wv[2 * q + 1].x) | ((unsigned)f2bf(wv[2 * q + 1].y) << 16);
      ww.w = (unsigned)f2bf(wv[2 * q + 1].z) | ((unsigned)f2bf(wv[2 * q + 1].w) << 16);
      lds[512 + wr * 8 + ((wc * 4 + q) ^ (wr & 7))] = ww;
    }
    __syncthreads();
#pragma unroll
    for (int ks = 0; ks < 2; ks++) {
      const int r0 = wm * 32 + l16, r1 = r0 + 16;
      short8 fa0 = *(const short8*)&lds[r0 * 8 + ((ks * 4 + lq) ^ (r0 & 7))];
      short8 fa1 = *(const short8*)&lds[r1 * 8 + ((ks * 4 + lq) ^ (r1 & 7))];
#pragma unroll
      for (int fn = 0; fn < 4; fn++) {
        const int bn = wn * 64 + fn * 16 + l16;
        short8 fb = *(const short8*)&lds[512 + bn * 8 + ((ks * 4 + lq) ^ (bn & 7))];
        acc[0][fn] = __builtin_amdgcn_mfma_f32_16x16x32_bf16(fa0, fb, acc[0][fn], 0, 0, 0);
        acc[1][fn] = __builtin_amdgcn_mfma_f32_16x16x32_bf16(fa1, fb, acc[1][fn], 0, 0, 0);
      }
    }
  }
  // epilogue: whT'[n][pi(m)] (4 m-values scatter by 64 under pi)
#pragma unroll
  for (int fm = 0; fm < 2; fm++) {
#pragma unroll
    for (int fn = 0; fn < 4; fn++) {
      const int n = wn * 64 + fn * 16 + l16;
      const int m0 = i0 + wm * 32 + fm * 16 + lq * 4;
      const int base = (m0 & ~255) | ((m0 >> 2) & 63);
#pragma unroll
      for (int r = 0; r < 4; r++)
        whT[(size_t)n * 8192 + (base | (r << 6))] = f2bf(acc[fm][fn][r]);
    }
  }
}

// ---------------- fused masked softmax-numerator x wh (bitmask, split-K=8) ----------------
// grid 512 = 64 row-blocks (BM=128) x 8 K-splits (1024 j); 512 thr = 8 waves
// = 4 row-groups (32 rows) x 2 col-halves (128 cols). NT=16 rounds of BK=64 j.
__global__ __launch_bounds__(512, 4) void k_attn(
    const unsigned long long* __restrict__ bm, const unsigned short* __restrict__ whT,
    const float* __restrict__ wh1v, const float* __restrict__ wh2v,
    const float* __restrict__ gmax,
    float* __restrict__ out0, float* __restrict__ parts,
    float* __restrict__ denp) {
  __shared__ uint4 ring[2][2048];  // 2 x 32KB whT tile [256 n][64 j] bf16
  __shared__ float wh2s[1024];     // this split's wh2' slice
  const int NT = 16;
  const int tid = threadIdx.x;
  const int bid = blockIdx.x;
  const int sb = bid & 7;      // one split per XCD -> bm/whT slices L2-resident
  const int mb = bid >> 3;     // 0..63
  const int i0 = mb * 128;
  const int jbase = sb * 1024;
  const int lane = tid & 63, wid = tid >> 6;
  const int wm = wid >> 1, wn = wid & 1;  // 4 row-groups x 2 col-halves
  const int l16 = lane & 15, q = lane >> 4;
  const int row_lo = i0 + wm * 32 + l16;

  if (tid < 256) ((float4*)wh2s)[tid] = ((const float4*)(wh2v + jbase))[tid];

  const float M2 = gmax[0];
  const float w1lo = wh1v[row_lo];
  const float w1hi = wh1v[row_lo + 16];
  float tv = w1lo + M2;
  const float Milo = tv > 0.f ? tv : 0.2f * tv;
  tv = w1hi + M2;
  const float Mihi = tv > 0.f ? tv : 0.2f * tv;
  const float c1lo = w1lo - Milo, c2lo = 0.2f * w1lo - Milo;
  const float c1hi = w1hi - Mihi, c2hi = 0.2f * w1hi - Mihi;

  const unsigned long long* bmp_lo = bm + (size_t)row_lo * 128 + sb * 16;
  const unsigned long long* bmp_hi = bmp_lo + 16 * 128;

  f32x4 accL[8] = {}, accH[8] = {};
  float dsL = 0.f, dsH = 0.f;
  short8 paL0, paL1, paH0, paH1;
  unsigned long long PAlo, PAhi, PBlo, PBhi;

#define PFLOAD(Rlo, Rhi, T)                       \
  do {                                            \
    const int t_ = ((T) < NT) ? (T) : 0;          \
    Rlo = bmp_lo[t_];                             \
    Rhi = bmp_hi[t_];                             \
  } while (0)

#define COMPUTE(Rlo, Rhi, T)                                                   \
  do {                                                                         \
    const int o_ = (((T) < NT) ? (T) : 0) * 64 + q * 8;                        \
    float4 z0 = *(const float4*)(wh2s + o_);                                   \
    float4 z1 = *(const float4*)(wh2s + o_ + 4);                               \
    float4 z2 = *(const float4*)(wh2s + o_ + 32);                              \
    float4 z3 = *(const float4*)(wh2s + o_ + 36);                              \
    float zv[16] = {z0.x, z0.y, z0.z, z0.w, z1.x, z1.y, z1.z, z1.w,            \
                    z2.x, z2.y, z2.z, z2.w, z3.x, z3.y, z3.z, z3.w};           \
    {                                                                          \
      const unsigned ms0 = (unsigned)(Rlo >> (q * 8));                         \
      const unsigned ms1 = (unsigned)(Rlo >> (32 + q * 8));                    \
      float pl[16];                                                            \
      _Pragma("unroll") for (int i = 0; i < 16; i++) {                         \
        float e1 = fmaxf(c1lo + zv[i], __builtin_fmaf(0.2f, zv[i], c2lo));     \
        const unsigned mbit = (i < 8) ? (ms0 >> i) : (ms1 >> (i - 8));         \
        float p = (mbit & 1u) ? __builtin_amdgcn_exp2f(e1) : 0.f;              \
        pl[i] = p;                                                             \
        dsL += p;                                                              \
      }                                                                        \
      _Pragma("unroll") for (int i = 0; i < 8; i++) {                          \
        paL0[i] = (short)f2bf(pl[i]);                                          \
        paL1[i] = (short)f2bf(pl[8 + i]);                                      \
      }                                                                        \
    }                                                                          \
    {                                                                          \
      const unsigned ms0 = (unsigned)(Rhi >> (q * 8));                         \
      const unsigned ms1 = (unsigned)(Rhi >> (32 + q * 8));                    \
      float ph[16];                                                            \
      _Pragma("unroll") for (int i = 0; i < 16; i++) {                         \
        float e2 = fmaxf(c1hi + zv[i], __builtin_fmaf(0.2f, zv[i], c2hi));     \
        const unsigned mbit = (i < 8) ? (ms0 >> i) : (ms1 >> (i - 8));         \
        float p = (mbit & 1u) ? __builtin_amdgcn_exp2f(e2) : 0.f;              \
        ph[i] = p;                                                             \
        dsH += p;                                                              \
      }                                                                        \
      _Pragma("unroll") for (int i = 0; i < 8; i++) {                          \
        paH0[i] = (short)f2bf(ph[i]);                                          \
        paH1[i] = (short)f2bf(ph[8 + i]);                                      \
      }                                                                        \
    }                                                                          \
  } while (0)

#define STAGE(TT, SLOT)                                                        \
  do {                                                                         \
    const int tt_ = ((TT) < NT) ? (TT) : 0;                                    \
    const size_t gj_ = (size_t)(jbase + tt_ * 64);                             \
    _Pragma("unroll") for (int kq = 0; kq < 4; kq++) {                         \
      const int L = kq * 512 + tid;                                            \
      const int row = L >> 3, sub = L & 7;                                     \
      const int boff = (sub * 16) ^ ((row & 7) << 4);                          \
      const char* src_ = (const char*)(whT + (size_t)row * 8192 + gj_) + boff; \
      char* dst_ = (char*)ring[SLOT] + L * 16;                                 \
      __builtin_amdgcn_global_load_lds(                                        \
          (const __attribute__((address_space(1))) unsigned int*)src_,         \
          (__attribute__((address_space(3))) unsigned int*)dst_, 16, 0, 0);    \
    }                                                                          \
  } while (0)

#define FENCE asm volatile("s_waitcnt vmcnt(2)" ::: "memory")

#define MFMAPH(SLOT)                                                           \
  do {                                                                         \
    const char* lb_ = (const char*)ring[SLOT];                                 \
    _Pragma("unroll") for (int nb = 0; nb < 8; nb++) {                         \
      const int n_ = wn * 128 + nb * 16 + l16;                                 \
      const int rb_ = n_ * 128;                                                \
      const int sw_ = (n_ & 7) << 4;                                           \
      short8 fb0 = *(const short8*)(lb_ + rb_ + ((q * 16) ^ sw_));             \
      short8 fb1 = *(const short8*)(lb_ + rb_ + ((64 + q * 16) ^ sw_));        \
      accL[nb] = __builtin_amdgcn_mfma_f32_16x16x32_bf16(paL0, fb0, accL[nb], 0, 0, 0); \
      accL[nb] = __builtin_amdgcn_mfma_f32_16x16x32_bf16(paL1, fb1, accL[nb], 0, 0, 0); \
      accH[nb] = __builtin_amdgcn_mfma_f32_16x16x32_bf16(paH0, fb0, accH[nb], 0, 0, 0); \
      accH[nb] = __builtin_amdgcn_mfma_f32_16x16x32_bf16(paH1, fb1, accH[nb], 0, 0, 0); \
    }                                                                          \
  } while (0)

  // prologue
  PFLOAD(PAlo, PAhi, 0);
  STAGE(0, 0);
  __syncthreads();  // wh2s visible

  for (int t = 0; t < NT; t += 2) {
    // even round: reads ring[0]
    PFLOAD(PBlo, PBhi, t + 1);
    COMPUTE(PAlo, PAhi, t);
    FENCE;
    __builtin_amdgcn_s_barrier();
    STAGE(t + 1, 1);
    MFMAPH(0);
    // odd round: reads ring[1]
    PFLOAD(PAlo, PAhi, t + 2);
    COMPUTE(PBlo, PBhi, t + 1);
    FENCE;
    __builtin_amdgcn_s_barrier();
    STAGE(t + 2, 0);
    MFMAPH(1);
  }

#undef PFLOAD
#undef COMPUTE
#undef STAGE
#undef FENCE
#undef MFMAPH

  float* outp = (sb == 0) ? out0 : parts + (size_t)(sb - 1) * 2097152;
  const int r0 = i0 + wm * 32 + q * 4;
#pragma unroll
  for (int nb = 0; nb < 8; nb++) {
    const int col = wn * 128 + nb * 16 + l16;
#pragma unroll
    for (int r = 0; r < 4; r++) {
      outp[(size_t)(r0 + r) * 256 + col] = accL[nb][r];
      outp[(size_t)(r0 + 16 + r) * 256 + col] = accH[nb][r];
    }
  }

  // denom: P duplicated across wn halves -> only wn==0 writes
  dsL += __shfl_xor(dsL, 16);
  dsL += __shfl_xor(dsL, 32);
  dsH += __shfl_xor(dsH, 16);
  dsH += __shfl_xor(dsH, 32);
  if (wn == 0 && lane < 16) {
    denp[sb * 8192 + i0 + wm * 32 + lane] = dsL;
    denp[sb * 8192 + i0 + wm * 32 + 16 + lane] = dsH;
  }
}

// ---------------- combine 8 split-K partials, divide by denom, elu ----------------
__global__ __launch_bounds__(256) void k_out(float* __restrict__ out,
                                             const float* __restrict__ parts,
                                             const float* __restrict__ denp) {
  const int idx = blockIdx.x * 256 + threadIdx.x;  // grid 2048
  const int row = idx >> 6;
  float4 o = ((const float4*)out)[idx];
  float den = denp[row];
#pragma unroll
  for (int s = 1; s < 8; s++) {
    float4 p = ((const float4*)(parts + (size_t)(s - 1) * 2097152))[idx];
    o.x += p.x; o.y += p.y; o.z += p.z; o.w += p.w;
    den += denp[s * 8192 + row];
  }
  const float inv = 1.0f / den;
  float v0 = o.x * inv, v1 = o.y * inv, v2 = o.z * inv, v3 = o.w * inv;
  v0 = v0 > 0.f ? v0 : expm1f(v0);
  v1 = v1 > 0.f ? v1 : expm1f(v1);
  v2 = v2 > 0.f ? v2 : expm1f(v2);
  v3 = v3 > 0.f ? v3 : expm1f(v3);
  ((float4*)out)[idx] = make_float4(v0, v1, v2, v3);
}

extern "C" void kernel_launch(void* const* d_in, const int* in_sizes, int n_in,
                              void* d_out, int out_size, void* d_ws, size_t ws_size,
                              hipStream_t stream) {
  const float* h = (const float*)d_in[0];
  const float* W = (const float*)d_in[1];
  const float* a1 = (const float*)d_in[2];
  const float* a2 = (const float*)d_in[3];
  const int* adj = (const int*)d_in[4];
  float* out = (float*)d_out;
  char* ws = (char*)d_ws;

  // ws: [whT 4MB][parts 7x8MB @4..60MB][denp+vecs @60MB][bm 8MB @61MB]
  unsigned short* whT = (unsigned short*)ws;
  float* parts = (float*)(ws + (4u << 20));
  float* denp = (float*)(ws + (60u << 20));  // 8*8192
  float* wh1 = denp + 8 * 8192;
  float* wh2 = wh1 + 8192;
  float* pmax = wh2 + 8192;  // 2048
  float* u1 = pmax + 2048;
  float* u2 = u1 + 512;
  float* gmax = u2 + 512;
  unsigned long long* bm = (unsigned long long*)(ws + (61u << 20));  // 8MB

  hipLaunchKernelGGL(k_mask, dim3(2048), dim3(256), 0, stream, adj, bm);
  hipLaunchKernelGGL(k_u, dim3(16), dim3(512), 0, stream, W, a1, a2, u1, u2);
  hipLaunchKernelGGL(k_rowvec, dim3(2048), dim3(256), 0, stream, h, u1, u2, wh1,
                     wh2, pmax);
  hipLaunchKernelGGL(k_wh, dim3(128), dim3(512), 0, stream, h, W, whT, pmax, gmax);
  hipLaunchKernelGGL(k_attn, dim3(512), dim3(512), 0, stream, bm, whT, wh1,
                     wh2, gmax, out, parts, denp);
  hipLaunchKernelGGL(k_out, dim3(2048), dim3(256), 0, stream, out, parts, denp);
  (void)in_sizes; (void)n_in; (void)out_size; (void)ws_size;
}

// Round 11
// 216.009 us; speedup vs baseline: 1.4684x; 1.4684x over previous
//
#include <hip/hip_runtime.h>

// GAT layer, N=8192, F_in=512, F_out=256.
// Pipeline: k_zero (out,denp) -> k_u -> k_rowvec (wh1,wh2 *log2e, blockmax)
//   -> k_wh (whT[f][j] bf16 GEMM; block 0 reduces pmax->gmax)
//   -> k_attn (static-B-in-registers: block = 512-row stream x 512-j chunk;
//      per round: adj stream -> P regs -> LDS P-tile -> MFMA -> f32 atomicAdd)
//   -> k_out (divide by denom + elu, in place)

typedef __attribute__((ext_vector_type(8))) short short8;
typedef __attribute__((ext_vector_type(4))) float f32x4;

#define LOG2E 1.4426950408889634f

__device__ __forceinline__ unsigned short f2bf(float f) {
  unsigned int u = __float_as_uint(f);
  unsigned int r = u + 0x7FFFu + ((u >> 16) & 1u);  // RNE
  return (unsigned short)(r >> 16);
}

// ---------------- zero the accumulation buffer + denom ----------------
__global__ __launch_bounds__(256) void k_zero(float* __restrict__ o,
                                              float* __restrict__ denp) {
  const int idx = blockIdx.x * 256 + threadIdx.x;  // grid 2048
  ((float4*)o)[idx] = make_float4(0.f, 0.f, 0.f, 0.f);
  if (idx < 8192) denp[idx] = 0.f;
}

// ---------------- u1 = W^T a1, u2 = W^T a2 (512 each), atomic-free ----------------
__global__ __launch_bounds__(512) void k_u(const float* __restrict__ W,
                                           const float* __restrict__ a1,
                                           const float* __restrict__ a2,
                                           float* __restrict__ u1,
                                           float* __restrict__ u2) {
  __shared__ float p1[16][32], p2[16][32];
  const int tid = threadIdx.x;
  const int kk = tid & 31, og = tid >> 5;
  const int k0 = blockIdx.x * 32;  // grid 16
  float s1 = 0.f, s2 = 0.f;
#pragma unroll
  for (int j = 0; j < 16; j++) {
    const int o = og * 16 + j;
    const float w = W[(size_t)o * 512 + k0 + kk];
    s1 += w * a1[o];
    s2 += w * a2[o];
  }
  p1[og][kk] = s1;
  p2[og][kk] = s2;
  __syncthreads();
  if (tid < 32) {
    float t1 = 0.f, t2 = 0.f;
#pragma unroll
    for (int g = 0; g < 16; g++) { t1 += p1[g][tid]; t2 += p2[g][tid]; }
    u1[k0 + tid] = t1;
    u2[k0 + tid] = t2;
  }
}

// --- wh1[i]=h_i.u1 * log2e, wh2[i]=h_i.u2 * log2e, per-block max(wh2) ---
__global__ __launch_bounds__(256) void k_rowvec(const float* __restrict__ h,
                                                const float* __restrict__ u1,
                                                const float* __restrict__ u2,
                                                float* __restrict__ wh1,
                                                float* __restrict__ wh2,
                                                float* __restrict__ pmax) {
  __shared__ float su1[512], su2[512];
  __shared__ float smax[4];
  const int tid = threadIdx.x;
  for (int i = tid; i < 512; i += 256) { su1[i] = u1[i]; su2[i] = u2[i]; }
  __syncthreads();
  const int lane = tid & 63;
  const int row = blockIdx.x * 4 + (tid >> 6);  // grid 2048
  const float* hp = h + (size_t)row * 512 + lane * 8;
  float4 x0 = *(const float4*)hp;
  float4 x1 = *(const float4*)(hp + 4);
  const float* q1 = su1 + lane * 8;
  const float* q2 = su2 + lane * 8;
  float s1 = x0.x * q1[0] + x0.y * q1[1] + x0.z * q1[2] + x0.w * q1[3]
           + x1.x * q1[4] + x1.y * q1[5] + x1.z * q1[6] + x1.w * q1[7];
  float s2 = x0.x * q2[0] + x0.y * q2[1] + x0.z * q2[2] + x0.w * q2[3]
           + x1.x * q2[4] + x1.y * q2[5] + x1.z * q2[6] + x1.w * q2[7];
#pragma unroll
  for (int off = 32; off >= 1; off >>= 1) {
    s1 += __shfl_xor(s1, off);
    s2 += __shfl_xor(s2, off);
  }
  if (lane == 0) {
    wh1[row] = s1 * LOG2E;
    wh2[row] = s2 * LOG2E;
    smax[tid >> 6] = s2 * LOG2E;
  }
  __syncthreads();
  if (tid == 0)
    pmax[blockIdx.x] = fmaxf(fmaxf(smax[0], smax[1]), fmaxf(smax[2], smax[3]));
}

// ------- whT[f][j] = (h @ W^T)[j][f] in bf16; block 0 also reduces pmax -> gmax -------
__global__ __launch_bounds__(512, 1) void k_wh(const float* __restrict__ h,
                                               const float* __restrict__ W,
                                               unsigned short* __restrict__ whT,
                                               const float* __restrict__ pmax,
                                               float* __restrict__ gmax) {
  __shared__ uint4 lds[2560];
  __shared__ float sred[8];
  const int tid = threadIdx.x;
  if (blockIdx.x == 0) {  // fold k_max
    float m = -3.0e38f;
    for (int i = tid; i < 2048; i += 512) m = fmaxf(m, pmax[i]);
#pragma unroll
    for (int off = 32; off >= 1; off >>= 1) m = fmaxf(m, __shfl_xor(m, off));
    if ((tid & 63) == 0) sred[tid >> 6] = m;
    __syncthreads();
    if (tid == 0) {
      float g = sred[0];
#pragma unroll
      for (int i = 1; i < 8; i++) g = fmaxf(g, sred[i]);
      gmax[0] = g;
    }
  }
  const int i0 = blockIdx.x * 64;  // grid 128
  const int lane = tid & 63, wid = tid >> 6;
  const int wm = wid >> 2, wn = wid & 3;
  const int l16 = lane & 15, lq = lane >> 4;
  const int hr = tid >> 3, hc = tid & 7;
  const int wr = tid >> 1, wc = tid & 1;

  f32x4 acc[2][4] = {};

  for (int t = 0; t < 8; t++) {
    const int k0 = t * 64;
    const float* hp = h + (size_t)(i0 + hr) * 512 + k0 + hc * 8;
    float4 hx = *(const float4*)hp;
    float4 hy = *(const float4*)(hp + 4);
    const float* wp = W + (size_t)wr * 512 + k0 + wc * 32;
    float4 wv[8];
#pragma unroll
    for (int q = 0; q < 8; q++) wv[q] = *(const float4*)(wp + q * 4);

    __syncthreads();
    uint4 hw;
    hw.x = (unsigned)f2bf(hx.x) | ((unsigned)f2bf(hx.y) << 16);
    hw.y = (unsigned)f2bf(hx.z) | ((unsigned)f2bf(hx.w) << 16);
    hw.z = (unsigned)f2bf(hy.x) | ((unsigned)f2bf(hy.y) << 16);
    hw.w = (unsigned)f2bf(hy.z) | ((unsigned)f2bf(hy.w) << 16);
    lds[hr * 8 + (hc ^ (hr & 7))] = hw;
#pragma unroll
    for (int q = 0; q < 4; q++) {
      uint4 ww;
      ww.x = (unsigned)f2bf(wv[2 * q].x) | ((unsigned)f2bf(wv[2 * q].y) << 16);
      ww.y = (unsigned)f2bf(wv[2 * q].z) | ((unsigned)f2bf(wv[2 * q].w) << 16);
      ww.z = (unsigned)f2bf(wv[2 * q + 1].x) | ((unsigned)f2bf(wv[2 * q + 1].y) << 16);
      ww.w = (unsigned)f2bf(wv[2 * q + 1].z) | ((unsigned)f2bf(wv[2 * q + 1].w) << 16);
      lds[512 + wr * 8 + ((wc * 4 + q) ^ (wr & 7))] = ww;
    }
    __syncthreads();
#pragma unroll
    for (int ks = 0; ks < 2; ks++) {
      const int r0 = wm * 32 + l16, r1 = r0 + 16;
      short8 fa0 = *(const short8*)&lds[r0 * 8 + ((ks * 4 + lq) ^ (r0 & 7))];
      short8 fa1 = *(const short8*)&lds[r1 * 8 + ((ks * 4 + lq) ^ (r1 & 7))];
#pragma unroll
      for (int fn = 0; fn < 4; fn++) {
        const int bn = wn * 64 + fn * 16 + l16;
        short8 fb = *(const short8*)&lds[512 + bn * 8 + ((ks * 4 + lq) ^ (bn & 7))];
        acc[0][fn] = __builtin_amdgcn_mfma_f32_16x16x32_bf16(fa0, fb, acc[0][fn], 0, 0, 0);
        acc[1][fn] = __builtin_amdgcn_mfma_f32_16x16x32_bf16(fa1, fb, acc[1][fn], 0, 0, 0);
      }
    }
  }
#pragma unroll
  for (int fm = 0; fm < 2; fm++) {
#pragma unroll
    for (int fn = 0; fn < 4; fn++) {
      const int n = wn * 64 + fn * 16 + l16;
      const int m0 = i0 + wm * 32 + fm * 16 + lq * 4;
      uint2 o;
      o.x = (unsigned)f2bf(acc[fm][fn][0]) | ((unsigned)f2bf(acc[fm][fn][1]) << 16);
      o.y = (unsigned)f2bf(acc[fm][fn][2]) | ((unsigned)f2bf(acc[fm][fn][3]) << 16);
      *(uint2*)(whT + (size_t)n * 8192 + m0) = o;
    }
  }
}

// ---------------- fused masked softmax-numerator x wh (static-B) ----------------
// grid 256 = 16 row-blocks (512 rows) x 16 j-splits (512 j). 512 thr = 8 waves,
// wave w owns f-slice [w*32, w*32+32) with B = wh[jchunk][f-slice] in 128 VGPRs.
// 16 rounds of 32 rows: adj stream -> P regs -> swizzled LDS tile -> MFMA -> atomicAdd.
__global__ __launch_bounds__(512, 1) void k_attn(
    const int* __restrict__ adj, const unsigned short* __restrict__ whT,
    const float* __restrict__ wh1v, const float* __restrict__ wh2v,
    const float* __restrict__ gmax, float* __restrict__ outacc,
    float* __restrict__ denp) {
  __shared__ unsigned short pbuf[2][32 * 512];  // 2 x 32 KB P tiles (swizzled)
  const int tid = threadIdx.x;
  const int bid = blockIdx.x;
  const int sb = ((bid & 7) << 1) | ((bid >> 3) & 1);  // j-split 0..15 (XCD-paired)
  const int mbk = bid >> 4;                            // row-block 0..15
  const int rowbase = mbk * 512;
  const int jbase = sb * 512;
  const int lane = tid & 63, w = tid >> 6;
  const int l16 = lane & 15, q = lane >> 4;
  const int pr = tid >> 4, pc = tid & 15;  // producer: row 0..31, j-chunk 0..15

  // static B: B[k=j][n=f]; lane (l16 -> f, q -> k-chunk of 8 j)
  short8 B[16][2];
#pragma unroll
  for (int ks = 0; ks < 16; ks++)
#pragma unroll
    for (int nb = 0; nb < 2; nb++)
      B[ks][nb] = *(const short8*)(whT +
                                   (size_t)(w * 32 + nb * 16 + l16) * 8192 +
                                   jbase + ks * 32 + q * 8);

  // loop-invariant wh2 window for this thread's 32 j
  float zv[32];
#pragma unroll
  for (int c = 0; c < 8; c++)
    *(float4*)(zv + c * 4) = *(const float4*)(wh2v + jbase + pc * 32 + c * 4);

  const float M2 = gmax[0];
  const int* adjp = adj + (size_t)(rowbase + pr) * 8192 + jbase + pc * 32;

  int4 PF[8];
#pragma unroll
  for (int c = 0; c < 8; c++) PF[c] = ((const int4*)adjp)[c];  // round 0

  for (int t = 0; t < 16; t++) {
    // ---- produce P tile for rows [rowbase+t*32, +32) ----
    const float w1 = wh1v[rowbase + t * 32 + pr];
    const float tm = w1 + M2;
    const float Mi = tm > 0.f ? tm : 0.2f * tm;  // exact softmax shift bound
    const float c1 = w1 - Mi, c2 = 0.2f * w1 - Mi;
    float dsum = 0.f;
    {
      char* pb = (char*)pbuf[t & 1];
      const int rb = pr * 1024;
      const int swz = (pr & 7) << 4;
#pragma unroll
      for (int c = 0; c < 4; c++) {  // 8 j per chunk -> one b128 write
        const int av[8] = {PF[2 * c].x,     PF[2 * c].y,     PF[2 * c].z,
                           PF[2 * c].w,     PF[2 * c + 1].x, PF[2 * c + 1].y,
                           PF[2 * c + 1].z, PF[2 * c + 1].w};
        unsigned pw[4];
#pragma unroll
        for (int i = 0; i < 4; i++) {
          const float za = zv[c * 8 + 2 * i], zb = zv[c * 8 + 2 * i + 1];
          float e0 = fmaxf(c1 + za, __builtin_fmaf(0.2f, za, c2));
          float p0 = (av[2 * i] > 0) ? __builtin_amdgcn_exp2f(e0) : 0.f;
          float e1 = fmaxf(c1 + zb, __builtin_fmaf(0.2f, zb, c2));
          float p1 = (av[2 * i + 1] > 0) ? __builtin_amdgcn_exp2f(e1) : 0.f;
          dsum += p0 + p1;
          pw[i] = (unsigned)f2bf(p0) | ((unsigned)f2bf(p1) << 16);
        }
        *(uint4*)(pb + rb + ((pc * 64 + c * 16) ^ swz)) =
            make_uint4(pw[0], pw[1], pw[2], pw[3]);
      }
    }
    __syncthreads();
    if (t + 1 < 16) {  // prefetch next round's adj during MFMA phase
      const int4* ap_ = (const int4*)(adjp + (size_t)(t + 1) * 262144);
#pragma unroll
      for (int c = 0; c < 8; c++) PF[c] = ap_[c];
    }
    // ---- consume: MFMA over K=512 with static B ----
    f32x4 acc[2][2] = {};
    {
      const char* pb = (const char*)pbuf[t & 1];
#pragma unroll
      for (int mt = 0; mt < 2; mt++) {
        const int row = mt * 16 + l16;
        const int rb = row * 1024;
        const int swz = (row & 7) << 4;
#pragma unroll
        for (int ks = 0; ks < 16; ks++) {
          short8 A = *(const short8*)(pb + rb + ((ks * 64 + q * 16) ^ swz));
          acc[mt][0] = __builtin_amdgcn_mfma_f32_16x16x32_bf16(A, B[ks][0],
                                                               acc[mt][0], 0, 0, 0);
          acc[mt][1] = __builtin_amdgcn_mfma_f32_16x16x32_bf16(A, B[ks][1],
                                                               acc[mt][1], 0, 0, 0);
        }
      }
    }
    // ---- flush: f32 atomicAdd into accumulation buffer ----
    {
      const int rbase = rowbase + t * 32;
#pragma unroll
      for (int mt = 0; mt < 2; mt++) {
        const int r0 = rbase + mt * 16 + q * 4;
#pragma unroll
        for (int nb = 0; nb < 2; nb++) {
          const int f = w * 32 + nb * 16 + l16;
#pragma unroll
          for (int r = 0; r < 4; r++)
            atomicAdd(outacc + (size_t)(r0 + r) * 256 + f, acc[mt][nb][r]);
        }
      }
    }
    // ---- denom: reduce over the 16 pc-threads of each row ----
    dsum += __shfl_xor(dsum, 1);
    dsum += __shfl_xor(dsum, 2);
    dsum += __shfl_xor(dsum, 4);
    dsum += __shfl_xor(dsum, 8);
    if (pc == 0) atomicAdd(denp + rowbase + t * 32 + pr, dsum);
  }
}

// ---------------- divide by denom + elu, in place ----------------
__global__ __launch_bounds__(256) void k_out(float* __restrict__ out,
                                             const float* __restrict__ denp) {
  const int idx = blockIdx.x * 256 + threadIdx.x;  // grid 2048
  const int row = idx >> 6;
  float4 o = ((const float4*)out)[idx];
  const float inv = 1.0f / denp[row];
  float v0 = o.x * inv, v1 = o.y * inv, v2 = o.z * inv, v3 = o.w * inv;
  v0 = v0 > 0.f ? v0 : expm1f(v0);
  v1 = v1 > 0.f ? v1 : expm1f(v1);
  v2 = v2 > 0.f ? v2 : expm1f(v2);
  v3 = v3 > 0.f ? v3 : expm1f(v3);
  ((float4*)out)[idx] = make_float4(v0, v1, v2, v3);
}

extern "C" void kernel_launch(void* const* d_in, const int* in_sizes, int n_in,
                              void* d_out, int out_size, void* d_ws, size_t ws_size,
                              hipStream_t stream) {
  const float* h = (const float*)d_in[0];
  const float* W = (const float*)d_in[1];
  const float* a1 = (const float*)d_in[2];
  const float* a2 = (const float*)d_in[3];
  const int* adj = (const int*)d_in[4];
  float* out = (float*)d_out;
  char* ws = (char*)d_ws;

  // ws: [whT 4MB][denp 32K][wh1 32K][wh2 32K][pmax 8K][u1 2K][u2 2K][gmax]
  unsigned short* whT = (unsigned short*)ws;
  float* denp = (float*)(ws + (4u << 20));
  float* wh1 = denp + 8192;
  float* wh2 = wh1 + 8192;
  float* pmax = wh2 + 8192;  // 2048
  float* u1 = pmax + 2048;
  float* u2 = u1 + 512;
  float* gmax = u2 + 512;

  hipLaunchKernelGGL(k_zero, dim3(2048), dim3(256), 0, stream, out, denp);
  hipLaunchKernelGGL(k_u, dim3(16), dim3(512), 0, stream, W, a1, a2, u1, u2);
  hipLaunchKernelGGL(k_rowvec, dim3(2048), dim3(256), 0, stream, h, u1, u2, wh1,
                     wh2, pmax);
  hipLaunchKernelGGL(k_wh, dim3(128), dim3(512), 0, stream, h, W, whT, pmax, gmax);
  hipLaunchKernelGGL(k_attn, dim3(256), dim3(512), 0, stream, adj, whT, wh1,
                     wh2, gmax, out, denp);
  hipLaunchKernelGGL(k_out, dim3(2048), dim3(256), 0, stream, out, denp);
  (void)in_sizes; (void)n_in; (void)out_size; (void)ws_size;
}

// Round 12
// 192.877 us; speedup vs baseline: 1.6445x; 1.1199x over previous
//
#include <hip/hip_runtime.h>

// GAT layer, N=8192, F_in=512, F_out=256.
// Pipeline: k_u -> k_rowvec (wh1,wh2 *log2e, blockmax)
//   -> k_wh (whT[f][j] bf16 GEMM; block 0 reduces pmax->gmax)
//   -> k_attn (block = 32 rows x FULL j; static-B reloaded per 512-j chunk from
//      L2-resident whT; P tile in conflict-free swizzled LDS; acc in regs across
//      chunks; fused /denom + elu epilogue -> d_out. No atomics, no partials.)

typedef __attribute__((ext_vector_type(8))) short short8;
typedef __attribute__((ext_vector_type(4))) float f32x4;

#define LOG2E 1.4426950408889634f

__device__ __forceinline__ unsigned short f2bf(float f) {
  unsigned int u = __float_as_uint(f);
  unsigned int r = u + 0x7FFFu + ((u >> 16) & 1u);  // RNE
  return (unsigned short)(r >> 16);
}

// ---------------- u1 = W^T a1, u2 = W^T a2 (512 each), atomic-free ----------------
__global__ __launch_bounds__(512) void k_u(const float* __restrict__ W,
                                           const float* __restrict__ a1,
                                           const float* __restrict__ a2,
                                           float* __restrict__ u1,
                                           float* __restrict__ u2) {
  __shared__ float p1[16][32], p2[16][32];
  const int tid = threadIdx.x;
  const int kk = tid & 31, og = tid >> 5;
  const int k0 = blockIdx.x * 32;  // grid 16
  float s1 = 0.f, s2 = 0.f;
#pragma unroll
  for (int j = 0; j < 16; j++) {
    const int o = og * 16 + j;
    const float w = W[(size_t)o * 512 + k0 + kk];
    s1 += w * a1[o];
    s2 += w * a2[o];
  }
  p1[og][kk] = s1;
  p2[og][kk] = s2;
  __syncthreads();
  if (tid < 32) {
    float t1 = 0.f, t2 = 0.f;
#pragma unroll
    for (int g = 0; g < 16; g++) { t1 += p1[g][tid]; t2 += p2[g][tid]; }
    u1[k0 + tid] = t1;
    u2[k0 + tid] = t2;
  }
}

// --- wh1[i]=h_i.u1 * log2e, wh2[i]=h_i.u2 * log2e, per-block max(wh2) ---
__global__ __launch_bounds__(256) void k_rowvec(const float* __restrict__ h,
                                                const float* __restrict__ u1,
                                                const float* __restrict__ u2,
                                                float* __restrict__ wh1,
                                                float* __restrict__ wh2,
                                                float* __restrict__ pmax) {
  __shared__ float su1[512], su2[512];
  __shared__ float smax[4];
  const int tid = threadIdx.x;
  for (int i = tid; i < 512; i += 256) { su1[i] = u1[i]; su2[i] = u2[i]; }
  __syncthreads();
  const int lane = tid & 63;
  const int row = blockIdx.x * 4 + (tid >> 6);  // grid 2048
  const float* hp = h + (size_t)row * 512 + lane * 8;
  float4 x0 = *(const float4*)hp;
  float4 x1 = *(const float4*)(hp + 4);
  const float* q1 = su1 + lane * 8;
  const float* q2 = su2 + lane * 8;
  float s1 = x0.x * q1[0] + x0.y * q1[1] + x0.z * q1[2] + x0.w * q1[3]
           + x1.x * q1[4] + x1.y * q1[5] + x1.z * q1[6] + x1.w * q1[7];
  float s2 = x0.x * q2[0] + x0.y * q2[1] + x0.z * q2[2] + x0.w * q2[3]
           + x1.x * q2[4] + x1.y * q2[5] + x1.z * q2[6] + x1.w * q2[7];
#pragma unroll
  for (int off = 32; off >= 1; off >>= 1) {
    s1 += __shfl_xor(s1, off);
    s2 += __shfl_xor(s2, off);
  }
  if (lane == 0) {
    wh1[row] = s1 * LOG2E;
    wh2[row] = s2 * LOG2E;
    smax[tid >> 6] = s2 * LOG2E;
  }
  __syncthreads();
  if (tid == 0)
    pmax[blockIdx.x] = fmaxf(fmaxf(smax[0], smax[1]), fmaxf(smax[2], smax[3]));
}

// ------- whT[f][j] = (h @ W^T)[j][f] in bf16; block 0 also reduces pmax -> gmax -------
__global__ __launch_bounds__(512, 1) void k_wh(const float* __restrict__ h,
                                               const float* __restrict__ W,
                                               unsigned short* __restrict__ whT,
                                               const float* __restrict__ pmax,
                                               float* __restrict__ gmax) {
  __shared__ uint4 lds[2560];
  __shared__ float sred[8];
  const int tid = threadIdx.x;
  if (blockIdx.x == 0) {  // fold k_max
    float m = -3.0e38f;
    for (int i = tid; i < 2048; i += 512) m = fmaxf(m, pmax[i]);
#pragma unroll
    for (int off = 32; off >= 1; off >>= 1) m = fmaxf(m, __shfl_xor(m, off));
    if ((tid & 63) == 0) sred[tid >> 6] = m;
    __syncthreads();
    if (tid == 0) {
      float g = sred[0];
#pragma unroll
      for (int i = 1; i < 8; i++) g = fmaxf(g, sred[i]);
      gmax[0] = g;
    }
  }
  const int i0 = blockIdx.x * 64;  // grid 128
  const int lane = tid & 63, wid = tid >> 6;
  const int wm = wid >> 2, wn = wid & 3;
  const int l16 = lane & 15, lq = lane >> 4;
  const int hr = tid >> 3, hc = tid & 7;
  const int wr = tid >> 1, wc = tid & 1;

  f32x4 acc[2][4] = {};

  for (int t = 0; t < 8; t++) {
    const int k0 = t * 64;
    const float* hp = h + (size_t)(i0 + hr) * 512 + k0 + hc * 8;
    float4 hx = *(const float4*)hp;
    float4 hy = *(const float4*)(hp + 4);
    const float* wp = W + (size_t)wr * 512 + k0 + wc * 32;
    float4 wv[8];
#pragma unroll
    for (int q = 0; q < 8; q++) wv[q] = *(const float4*)(wp + q * 4);

    __syncthreads();
    uint4 hw;
    hw.x = (unsigned)f2bf(hx.x) | ((unsigned)f2bf(hx.y) << 16);
    hw.y = (unsigned)f2bf(hx.z) | ((unsigned)f2bf(hx.w) << 16);
    hw.z = (unsigned)f2bf(hy.x) | ((unsigned)f2bf(hy.y) << 16);
    hw.w = (unsigned)f2bf(hy.z) | ((unsigned)f2bf(hy.w) << 16);
    lds[hr * 8 + (hc ^ (hr & 7))] = hw;
#pragma unroll
    for (int q = 0; q < 4; q++) {
      uint4 ww;
      ww.x = (unsigned)f2bf(wv[2 * q].x) | ((unsigned)f2bf(wv[2 * q].y) << 16);
      ww.y = (unsigned)f2bf(wv[2 * q].z) | ((unsigned)f2bf(wv[2 * q].w) << 16);
      ww.z = (unsigned)f2bf(wv[2 * q + 1].x) | ((unsigned)f2bf(wv[2 * q + 1].y) << 16);
      ww.w = (unsigned)f2bf(wv[2 * q + 1].z) | ((unsigned)f2bf(wv[2 * q + 1].w) << 16);
      lds[512 + wr * 8 + ((wc * 4 + q) ^ (wr & 7))] = ww;
    }
    __syncthreads();
#pragma unroll
    for (int ks = 0; ks < 2; ks++) {
      const int r0 = wm * 32 + l16, r1 = r0 + 16;
      short8 fa0 = *(const short8*)&lds[r0 * 8 + ((ks * 4 + lq) ^ (r0 & 7))];
      short8 fa1 = *(const short8*)&lds[r1 * 8 + ((ks * 4 + lq) ^ (r1 & 7))];
#pragma unroll
      for (int fn = 0; fn < 4; fn++) {
        const int bn = wn * 64 + fn * 16 + l16;
        short8 fb = *(const short8*)&lds[512 + bn * 8 + ((ks * 4 + lq) ^ (bn & 7))];
        acc[0][fn] = __builtin_amdgcn_mfma_f32_16x16x32_bf16(fa0, fb, acc[0][fn], 0, 0, 0);
        acc[1][fn] = __builtin_amdgcn_mfma_f32_16x16x32_bf16(fa1, fb, acc[1][fn], 0, 0, 0);
      }
    }
  }
#pragma unroll
  for (int fm = 0; fm < 2; fm++) {
#pragma unroll
    for (int fn = 0; fn < 4; fn++) {
      const int n = wn * 64 + fn * 16 + l16;
      const int m0 = i0 + wm * 32 + fm * 16 + lq * 4;
      uint2 o;
      o.x = (unsigned)f2bf(acc[fm][fn][0]) | ((unsigned)f2bf(acc[fm][fn][1]) << 16);
      o.y = (unsigned)f2bf(acc[fm][fn][2]) | ((unsigned)f2bf(acc[fm][fn][3]) << 16);
      *(uint2*)(whT + (size_t)n * 8192 + m0) = o;
    }
  }
}

// ---------------- fused masked softmax x wh, full-j per block ----------------
// grid 256 = 8192/32 rows. 512 thr = 8 waves, wave w owns f-slice [w*32,w*32+32).
// 16 jc-chunks of 512 j: B regs reloaded per chunk; P tile double-buffered in LDS
// (swizzle byte = row*1024 + ((slot ^ (row&7))*16)); acc in regs across chunks.
__global__ __launch_bounds__(512, 1) void k_attn(
    const int* __restrict__ adj, const unsigned short* __restrict__ whT,
    const float* __restrict__ wh1v, const float* __restrict__ wh2v,
    const float* __restrict__ gmax, float* __restrict__ out) {
  __shared__ unsigned short pbuf[2][32 * 512];  // 2 x 32 KB P tiles
  __shared__ float wh2s[8192];                  // 32 KB
  __shared__ float dls[32];
  const int tid = threadIdx.x;
  const int rowbase = blockIdx.x * 32;  // grid 256
  const int lane = tid & 63, w = tid >> 6;
  const int l16 = lane & 15, q = lane >> 4;
  const int pr = tid >> 4, pc = tid & 15;  // producer: row 0..31, j-slot 0..15

  for (int i = tid; i < 2048; i += 512)
    ((float4*)wh2s)[i] = ((const float4*)wh2v)[i];

  const float M2 = gmax[0];
  const float w1 = wh1v[rowbase + pr];
  const float tm = w1 + M2;
  const float Mi = tm > 0.f ? tm : 0.2f * tm;  // exact per-row softmax shift bound
  const float c1 = w1 - Mi, c2 = 0.2f * w1 - Mi;

  const int* adjp = adj + (size_t)(rowbase + pr) * 8192;
  float dsum = 0.f;

  f32x4 acc[2][2] = {};
  short8 B[16][2];
  int4 PFa[8], PFb[8];

// adj loads for chunk JC -> reg set R (thread covers j = JC*512 + c*128 + pc*8)
#define PFLOAD(R, JC)                                                \
  do {                                                               \
    const int jj_ = ((JC) < 16) ? (JC) : 15;                         \
    const int* ap_ = adjp + jj_ * 512 + pc * 8;                      \
    _Pragma("unroll") for (int c = 0; c < 4; c++) {                  \
      R[2 * c] = *(const int4*)(ap_ + c * 128);                      \
      R[2 * c + 1] = *(const int4*)(ap_ + c * 128 + 4);              \
    }                                                                \
  } while (0)

// P for chunk JC from reg set R -> pbuf[BUF]; write slot = c*16+pc (conflict-free)
#define PRODUCE(JC, R, BUF)                                          \
  do {                                                               \
    char* pb_ = (char*)pbuf[BUF];                                    \
    const float* zb_ = wh2s + (JC) * 512 + pc * 8;                   \
    _Pragma("unroll") for (int c = 0; c < 4; c++) {                  \
      float4 za_ = *(const float4*)(zb_ + c * 128);                  \
      float4 zc_ = *(const float4*)(zb_ + c * 128 + 4);              \
      const float zv_[8] = {za_.x, za_.y, za_.z, za_.w,              \
                            zc_.x, zc_.y, zc_.z, zc_.w};             \
      const int av_[8] = {R[2 * c].x, R[2 * c].y, R[2 * c].z,        \
                          R[2 * c].w, R[2 * c + 1].x, R[2 * c + 1].y,\
                          R[2 * c + 1].z, R[2 * c + 1].w};           \
      unsigned pw_[4];                                               \
      _Pragma("unroll") for (int i = 0; i < 4; i++) {                \
        float z0_ = zv_[2 * i], z1_ = zv_[2 * i + 1];                \
        float e0_ = fmaxf(c1 + z0_, __builtin_fmaf(0.2f, z0_, c2));  \
        float p0_ = (av_[2 * i] > 0) ? __builtin_amdgcn_exp2f(e0_) : 0.f; \
        float e1_ = fmaxf(c1 + z1_, __builtin_fmaf(0.2f, z1_, c2));  \
        float p1_ = (av_[2 * i + 1] > 0) ? __builtin_amdgcn_exp2f(e1_) : 0.f; \
        dsum += p0_ + p1_;                                           \
        pw_[i] = (unsigned)f2bf(p0_) | ((unsigned)f2bf(p1_) << 16);  \
      }                                                              \
      const int sl_ = (c * 16 + pc) ^ (pr & 7);                      \
      *(uint4*)(pb_ + pr * 1024 + sl_ * 16) =                        \
          make_uint4(pw_[0], pw_[1], pw_[2], pw_[3]);                \
    }                                                                \
  } while (0)

// B regs for chunk JC: lane (l16->f, q->k-subchunk)
#define BRELOAD(JC)                                                  \
  do {                                                               \
    const unsigned short* wb_ = whT + (JC) * 512 + q * 8;            \
    _Pragma("unroll") for (int ks = 0; ks < 16; ks++) {              \
      B[ks][0] = *(const short8*)(wb_ + (size_t)(w * 32 + l16) * 8192 + ks * 32); \
      B[ks][1] = *(const short8*)(wb_ + (size_t)(w * 32 + 16 + l16) * 8192 + ks * 32); \
    }                                                                \
  } while (0)

#define MFMAPH(BUF)                                                  \
  do {                                                               \
    const char* pb_ = (const char*)pbuf[BUF];                        \
    _Pragma("unroll") for (int mt = 0; mt < 2; mt++) {               \
      const int row_ = mt * 16 + l16;                                \
      const char* rb_ = pb_ + row_ * 1024;                           \
      const int sx_ = row_ & 7;                                      \
      _Pragma("unroll") for (int ks = 0; ks < 16; ks++) {            \
        short8 A_ = *(const short8*)(rb_ + (((ks * 4 + q) ^ sx_) * 16)); \
        acc[mt][0] = __builtin_amdgcn_mfma_f32_16x16x32_bf16(A_, B[ks][0], acc[mt][0], 0, 0, 0); \
        acc[mt][1] = __builtin_amdgcn_mfma_f32_16x16x32_bf16(A_, B[ks][1], acc[mt][1], 0, 0, 0); \
      }                                                              \
    }                                                                \
  } while (0)

  // prologue
  PFLOAD(PFa, 0);
  PFLOAD(PFb, 1);
  BRELOAD(0);
  __syncthreads();  // wh2s visible
  PRODUCE(0, PFa, 0);
  __syncthreads();  // buf0 visible

  for (int t2 = 0; t2 < 8; t2++) {
    const int t = t2 * 2;
    // even round t: MFMA buf0 with B(t); produce(t+1)->buf1; prefetch t+2
    PFLOAD(PFa, t + 2);
    PRODUCE(t + 1, PFb, 1);
    MFMAPH(0);
    if (t + 1 < 16) BRELOAD(t + 1);
    __syncthreads();
    // odd round t+1: MFMA buf1 with B(t+1); produce(t+2)->buf0; prefetch t+3
    PFLOAD(PFb, t + 3);
    if (t + 2 < 16) PRODUCE(t + 2, PFa, 0);
    MFMAPH(1);
    if (t + 2 < 16) BRELOAD(t + 2);
    __syncthreads();
  }

#undef PFLOAD
#undef PRODUCE
#undef BRELOAD
#undef MFMAPH

  // denom: reduce across the 16 pc-threads of each row
  dsum += __shfl_xor(dsum, 1);
  dsum += __shfl_xor(dsum, 2);
  dsum += __shfl_xor(dsum, 4);
  dsum += __shfl_xor(dsum, 8);
  if (pc == 0) dls[pr] = dsum;
  __syncthreads();

  // epilogue: D lane (l16=f-col, q): rows mt*16 + q*4 + r
#pragma unroll
  for (int mt = 0; mt < 2; mt++)
#pragma unroll
    for (int r = 0; r < 4; r++) {
      const int row = mt * 16 + q * 4 + r;
      const float inv = 1.0f / dls[row];
#pragma unroll
      for (int nb = 0; nb < 2; nb++) {
        const int f = w * 32 + nb * 16 + l16;
        float v = acc[mt][nb][r] * inv;
        v = v > 0.f ? v : expm1f(v);
        out[(size_t)(rowbase + row) * 256 + f] = v;
      }
    }
}

extern "C" void kernel_launch(void* const* d_in, const int* in_sizes, int n_in,
                              void* d_out, int out_size, void* d_ws, size_t ws_size,
                              hipStream_t stream) {
  const float* h = (const float*)d_in[0];
  const float* W = (const float*)d_in[1];
  const float* a1 = (const float*)d_in[2];
  const float* a2 = (const float*)d_in[3];
  const int* adj = (const int*)d_in[4];
  float* out = (float*)d_out;
  char* ws = (char*)d_ws;

  // ws: [whT 4MB][wh1 32K][wh2 32K][pmax 8K][u1 2K][u2 2K][gmax]
  unsigned short* whT = (unsigned short*)ws;
  float* wh1 = (float*)(ws + (4u << 20));
  float* wh2 = wh1 + 8192;
  float* pmax = wh2 + 8192;  // 2048
  float* u1 = pmax + 2048;
  float* u2 = u1 + 512;
  float* gmax = u2 + 512;

  hipLaunchKernelGGL(k_u, dim3(16), dim3(512), 0, stream, W, a1, a2, u1, u2);
  hipLaunchKernelGGL(k_rowvec, dim3(2048), dim3(256), 0, stream, h, u1, u2, wh1,
                     wh2, pmax);
  hipLaunchKernelGGL(k_wh, dim3(128), dim3(512), 0, stream, h, W, whT, pmax, gmax);
  hipLaunchKernelGGL(k_attn, dim3(256), dim3(512), 0, stream, adj, whT, wh1,
                     wh2, gmax, out);
  (void)in_sizes; (void)n_in; (void)out_size; (void)ws_size;
}

// Round 13
// 161.300 us; speedup vs baseline: 1.9664x; 1.1958x over previous
//
#include <hip/hip_runtime.h>

// GAT layer, N=8192, F_in=512, F_out=256.
// Pipeline: k_u -> k_rowvec (wh1,wh2 *log2e, blockmax)
//   -> k_wh (whT bf16 GEMM; block 0 reduces pmax->gmax)
//   -> k_attn (r8 skeleton at 4 waves/block, BM=64, split-K=4, grid 512 =
//      2 INDEPENDENT blocks/CU so barriers of one are covered by the other;
//      P-in-registers; 2-slot global_load_lds ring + vmcnt(8) fence)
//   -> k_out (combine 4 partials + elu)

typedef __attribute__((ext_vector_type(8))) short short8;
typedef __attribute__((ext_vector_type(4))) float f32x4;

#define LOG2E 1.4426950408889634f

__device__ __forceinline__ unsigned short f2bf(float f) {
  unsigned int u = __float_as_uint(f);
  unsigned int r = u + 0x7FFFu + ((u >> 16) & 1u);  // RNE
  return (unsigned short)(r >> 16);
}

// ---------------- u1 = W^T a1, u2 = W^T a2 (512 each), atomic-free ----------------
__global__ __launch_bounds__(512) void k_u(const float* __restrict__ W,
                                           const float* __restrict__ a1,
                                           const float* __restrict__ a2,
                                           float* __restrict__ u1,
                                           float* __restrict__ u2) {
  __shared__ float p1[16][32], p2[16][32];
  const int tid = threadIdx.x;
  const int kk = tid & 31, og = tid >> 5;
  const int k0 = blockIdx.x * 32;  // grid 16
  float s1 = 0.f, s2 = 0.f;
#pragma unroll
  for (int j = 0; j < 16; j++) {
    const int o = og * 16 + j;
    const float w = W[(size_t)o * 512 + k0 + kk];
    s1 += w * a1[o];
    s2 += w * a2[o];
  }
  p1[og][kk] = s1;
  p2[og][kk] = s2;
  __syncthreads();
  if (tid < 32) {
    float t1 = 0.f, t2 = 0.f;
#pragma unroll
    for (int g = 0; g < 16; g++) { t1 += p1[g][tid]; t2 += p2[g][tid]; }
    u1[k0 + tid] = t1;
    u2[k0 + tid] = t2;
  }
}

// --- wh1[i]=h_i.u1 * log2e, wh2[i]=h_i.u2 * log2e, per-block max(wh2) ---
__global__ __launch_bounds__(256) void k_rowvec(const float* __restrict__ h,
                                                const float* __restrict__ u1,
                                                const float* __restrict__ u2,
                                                float* __restrict__ wh1,
                                                float* __restrict__ wh2,
                                                float* __restrict__ pmax) {
  __shared__ float su1[512], su2[512];
  __shared__ float smax[4];
  const int tid = threadIdx.x;
  for (int i = tid; i < 512; i += 256) { su1[i] = u1[i]; su2[i] = u2[i]; }
  __syncthreads();
  const int lane = tid & 63;
  const int row = blockIdx.x * 4 + (tid >> 6);  // grid 2048
  const float* hp = h + (size_t)row * 512 + lane * 8;
  float4 x0 = *(const float4*)hp;
  float4 x1 = *(const float4*)(hp + 4);
  const float* q1 = su1 + lane * 8;
  const float* q2 = su2 + lane * 8;
  float s1 = x0.x * q1[0] + x0.y * q1[1] + x0.z * q1[2] + x0.w * q1[3]
           + x1.x * q1[4] + x1.y * q1[5] + x1.z * q1[6] + x1.w * q1[7];
  float s2 = x0.x * q2[0] + x0.y * q2[1] + x0.z * q2[2] + x0.w * q2[3]
           + x1.x * q2[4] + x1.y * q2[5] + x1.z * q2[6] + x1.w * q2[7];
#pragma unroll
  for (int off = 32; off >= 1; off >>= 1) {
    s1 += __shfl_xor(s1, off);
    s2 += __shfl_xor(s2, off);
  }
  if (lane == 0) {
    wh1[row] = s1 * LOG2E;
    wh2[row] = s2 * LOG2E;
    smax[tid >> 6] = s2 * LOG2E;
  }
  __syncthreads();
  if (tid == 0)
    pmax[blockIdx.x] = fmaxf(fmaxf(smax[0], smax[1]), fmaxf(smax[2], smax[3]));
}

// ------- whT[n][m] = (h @ W^T)[m][n] in bf16; block 0 also reduces pmax -> gmax -------
__global__ __launch_bounds__(512, 1) void k_wh(const float* __restrict__ h,
                                               const float* __restrict__ W,
                                               unsigned short* __restrict__ whT,
                                               const float* __restrict__ pmax,
                                               float* __restrict__ gmax) {
  __shared__ uint4 lds[2560];
  __shared__ float sred[8];
  const int tid = threadIdx.x;
  if (blockIdx.x == 0) {  // fold k_max
    float m = -3.0e38f;
    for (int i = tid; i < 2048; i += 512) m = fmaxf(m, pmax[i]);
#pragma unroll
    for (int off = 32; off >= 1; off >>= 1) m = fmaxf(m, __shfl_xor(m, off));
    if ((tid & 63) == 0) sred[tid >> 6] = m;
    __syncthreads();
    if (tid == 0) {
      float g = sred[0];
#pragma unroll
      for (int i = 1; i < 8; i++) g = fmaxf(g, sred[i]);
      gmax[0] = g;
    }
  }
  const int i0 = blockIdx.x * 64;  // grid 128
  const int lane = tid & 63, wid = tid >> 6;
  const int wm = wid >> 2, wn = wid & 3;
  const int l16 = lane & 15, lq = lane >> 4;
  const int hr = tid >> 3, hc = tid & 7;
  const int wr = tid >> 1, wc = tid & 1;

  f32x4 acc[2][4] = {};

  for (int t = 0; t < 8; t++) {
    const int k0 = t * 64;
    const float* hp = h + (size_t)(i0 + hr) * 512 + k0 + hc * 8;
    float4 hx = *(const float4*)hp;
    float4 hy = *(const float4*)(hp + 4);
    const float* wp = W + (size_t)wr * 512 + k0 + wc * 32;
    float4 wv[8];
#pragma unroll
    for (int q = 0; q < 8; q++) wv[q] = *(const float4*)(wp + q * 4);

    __syncthreads();
    uint4 hw;
    hw.x = (unsigned)f2bf(hx.x) | ((unsigned)f2bf(hx.y) << 16);
    hw.y = (unsigned)f2bf(hx.z) | ((unsigned)f2bf(hx.w) << 16);
    hw.z = (unsigned)f2bf(hy.x) | ((unsigned)f2bf(hy.y) << 16);
    hw.w = (unsigned)f2bf(hy.z) | ((unsigned)f2bf(hy.w) << 16);
    lds[hr * 8 + (hc ^ (hr & 7))] = hw;
#pragma unroll
    for (int q = 0; q < 4; q++) {
      uint4 ww;
      ww.x = (unsigned)f2bf(wv[2 * q].x) | ((unsigned)f2bf(wv[2 * q].y) << 16);
      ww.y = (unsigned)f2bf(wv[2 * q].z) | ((unsigned)f2bf(wv[2 * q].w) << 16);
      ww.z = (unsigned)f2bf(wv[2 * q + 1].x) | ((unsigned)f2bf(wv[2 * q + 1].y) << 16);
      ww.w = (unsigned)f2bf(wv[2 * q + 1].z) | ((unsigned)f2bf(wv[2 * q + 1].w) << 16);
      lds[512 + wr * 8 + ((wc * 4 + q) ^ (wr & 7))] = ww;
    }
    __syncthreads();
#pragma unroll
    for (int ks = 0; ks < 2; ks++) {
      const int r0 = wm * 32 + l16, r1 = r0 + 16;
      short8 fa0 = *(const short8*)&lds[r0 * 8 + ((ks * 4 + lq) ^ (r0 & 7))];
      short8 fa1 = *(const short8*)&lds[r1 * 8 + ((ks * 4 + lq) ^ (r1 & 7))];
#pragma unroll
      for (int fn = 0; fn < 4; fn++) {
        const int bn = wn * 64 + fn * 16 + l16;
        short8 fb = *(const short8*)&lds[512 + bn * 8 + ((ks * 4 + lq) ^ (bn & 7))];
        acc[0][fn] = __builtin_amdgcn_mfma_f32_16x16x32_bf16(fa0, fb, acc[0][fn], 0, 0, 0);
        acc[1][fn] = __builtin_amdgcn_mfma_f32_16x16x32_bf16(fa1, fb, acc[1][fn], 0, 0, 0);
      }
    }
  }
#pragma unroll
  for (int fm = 0; fm < 2; fm++) {
#pragma unroll
    for (int fn = 0; fn < 4; fn++) {
      const int n = wn * 64 + fn * 16 + l16;
      const int m0 = i0 + wm * 32 + fm * 16 + lq * 4;
      uint2 o;
      o.x = (unsigned)f2bf(acc[fm][fn][0]) | ((unsigned)f2bf(acc[fm][fn][1]) << 16);
      o.y = (unsigned)f2bf(acc[fm][fn][2]) | ((unsigned)f2bf(acc[fm][fn][3]) << 16);
      *(uint2*)(whT + (size_t)n * 8192 + m0) = o;
    }
  }
}

// ---------------- fused masked softmax-numerator x wh ----------------
// grid 512 = 128 row-blocks (BM=64) x 4 K-splits (2048 j); 256 thr = 4 waves
// = 2 row-groups (32 rows) x 2 col-halves (128 cols). NT=32 rounds of BK=64 j.
// 72 KB LDS -> 2 independent blocks/CU: one block's barriers covered by the other.
struct PFR {
  int4 l0, l1, l2, l3, h0, h1, h2, h3;  // adj for lo/hi rows, 16 j each
};

__global__ __launch_bounds__(256, 2) void k_attn(
    const int* __restrict__ adj, const unsigned short* __restrict__ whT,
    const float* __restrict__ wh1v, const float* __restrict__ wh2v,
    const float* __restrict__ gmax,
    float* __restrict__ out0, float* __restrict__ out1,
    float* __restrict__ out2, float* __restrict__ out3,
    float* __restrict__ denp) {
  __shared__ uint4 ring[2][2048];  // 2 x 32KB whT tile [256 n][64 j] bf16
  __shared__ float wh2s[2048];     // this split's wh2 slice (log2e-scaled), 8KB
  const int NT = 32;
  const int tid = threadIdx.x;
  const int bid = blockIdx.x;
  const int sb = bid & 3;      // split; consecutive bids spread splits over XCDs
  const int mb = bid >> 2;     // 0..127
  const int i0 = mb * 64;
  const int jbase = sb * 2048;
  const int lane = tid & 63, wid = tid >> 6;
  const int wm = wid >> 1, wn = wid & 1;  // 2 row-groups x 2 col-halves
  const int l16 = lane & 15, q = lane >> 4;
  const int row_lo = i0 + wm * 32 + l16;

  for (int i = tid; i < 512; i += 256)
    ((float4*)wh2s)[i] = ((const float4*)(wh2v + jbase))[i];

  const float M2 = gmax[0];
  const float w1lo = wh1v[row_lo];
  const float w1hi = wh1v[row_lo + 16];
  float tv = w1lo + M2;
  const float Milo = tv > 0.f ? tv : 0.2f * tv;
  tv = w1hi + M2;
  const float Mihi = tv > 0.f ? tv : 0.2f * tv;
  const float c1lo = w1lo - Milo, c2lo = 0.2f * w1lo - Milo;
  const float c1hi = w1hi - Mihi, c2hi = 0.2f * w1hi - Mihi;

  const int* ap_lo = adj + (size_t)row_lo * 8192 + jbase + q * 8;
  const int* ap_hi = ap_lo + 16 * 8192;

  f32x4 accL[8] = {}, accH[8] = {};
  float dsL = 0.f, dsH = 0.f;
  short8 paL0, paL1, paH0, paH1;
  PFR PA, PB;

#define PFLOAD(R, T)                              \
  do {                                            \
    const int o_ = (((T) < NT) ? (T) : 0) * 64;   \
    R.l0 = *(const int4*)(ap_lo + o_);            \
    R.l1 = *(const int4*)(ap_lo + o_ + 4);        \
    R.l2 = *(const int4*)(ap_lo + o_ + 32);       \
    R.l3 = *(const int4*)(ap_lo + o_ + 36);       \
    R.h0 = *(const int4*)(ap_hi + o_);            \
    R.h1 = *(const int4*)(ap_hi + o_ + 4);        \
    R.h2 = *(const int4*)(ap_hi + o_ + 32);       \
    R.h3 = *(const int4*)(ap_hi + o_ + 36);       \
  } while (0)

#define COMPUTE(R, T)                                                          \
  do {                                                                         \
    const int o_ = (((T) < NT) ? (T) : 0) * 64 + q * 8;                        \
    float4 z0 = *(const float4*)(wh2s + o_);                                   \
    float4 z1 = *(const float4*)(wh2s + o_ + 4);                               \
    float4 z2 = *(const float4*)(wh2s + o_ + 32);                              \
    float4 z3 = *(const float4*)(wh2s + o_ + 36);                              \
    float zv[16] = {z0.x, z0.y, z0.z, z0.w, z1.x, z1.y, z1.z, z1.w,            \
                    z2.x, z2.y, z2.z, z2.w, z3.x, z3.y, z3.z, z3.w};           \
    int al[16] = {R.l0.x, R.l0.y, R.l0.z, R.l0.w, R.l1.x, R.l1.y, R.l1.z,      \
                  R.l1.w, R.l2.x, R.l2.y, R.l2.z, R.l2.w, R.l3.x, R.l3.y,      \
                  R.l3.z, R.l3.w};                                             \
    int ah[16] = {R.h0.x, R.h0.y, R.h0.z, R.h0.w, R.h1.x, R.h1.y, R.h1.z,      \
                  R.h1.w, R.h2.x, R.h2.y, R.h2.z, R.h2.w, R.h3.x, R.h3.y,      \
                  R.h3.z, R.h3.w};                                             \
    float pl[16], ph[16];                                                      \
    _Pragma("unroll") for (int i = 0; i < 16; i++) {                           \
      float e1 = fmaxf(c1lo + zv[i], __builtin_fmaf(0.2f, zv[i], c2lo));       \
      float p = (al[i] > 0) ? __builtin_amdgcn_exp2f(e1) : 0.f;                \
      pl[i] = p;                                                               \
      dsL += p;                                                                \
      float e2 = fmaxf(c1hi + zv[i], __builtin_fmaf(0.2f, zv[i], c2hi));       \
      p = (ah[i] > 0) ? __builtin_amdgcn_exp2f(e2) : 0.f;                      \
      ph[i] = p;                                                               \
      dsH += p;                                                                \
    }                                                                          \
    _Pragma("unroll") for (int i = 0; i < 8; i++) {                            \
      paL0[i] = (short)f2bf(pl[i]);                                            \
      paL1[i] = (short)f2bf(pl[8 + i]);                                        \
      paH0[i] = (short)f2bf(ph[i]);                                            \
      paH1[i] = (short)f2bf(ph[8 + i]);                                        \
    }                                                                          \
  } while (0)

#define STAGE(TT, SLOT)                                                        \
  do {                                                                         \
    const int tt_ = ((TT) < NT) ? (TT) : 0;                                    \
    const size_t gj_ = (size_t)(jbase + tt_ * 64);                             \
    _Pragma("unroll") for (int kq = 0; kq < 8; kq++) {                         \
      const int L = kq * 256 + tid;                                            \
      const int row = L >> 3, sub = L & 7;                                     \
      const int boff = (sub * 16) ^ ((row & 7) << 4);                          \
      const char* src_ = (const char*)(whT + (size_t)row * 8192 + gj_) + boff; \
      char* dst_ = (char*)ring[SLOT] + L * 16;                                 \
      __builtin_amdgcn_global_load_lds(                                        \
          (const __attribute__((address_space(1))) unsigned int*)src_,         \
          (__attribute__((address_space(3))) unsigned int*)dst_, 16, 0, 0);    \
    }                                                                          \
  } while (0)

#define FENCE asm volatile("s_waitcnt vmcnt(8)" ::: "memory")

#define MFMAPH(SLOT)                                                           \
  do {                                                                         \
    const char* lb_ = (const char*)ring[SLOT];                                 \
    _Pragma("unroll") for (int nb = 0; nb < 8; nb++) {                         \
      const int n_ = wn * 128 + nb * 16 + l16;                                 \
      const int rb_ = n_ * 128;                                                \
      const int sw_ = (n_ & 7) << 4;                                           \
      short8 fb0 = *(const short8*)(lb_ + rb_ + ((q * 16) ^ sw_));             \
      short8 fb1 = *(const short8*)(lb_ + rb_ + ((64 + q * 16) ^ sw_));        \
      accL[nb] = __builtin_amdgcn_mfma_f32_16x16x32_bf16(paL0, fb0, accL[nb], 0, 0, 0); \
      accL[nb] = __builtin_amdgcn_mfma_f32_16x16x32_bf16(paL1, fb1, accL[nb], 0, 0, 0); \
      accH[nb] = __builtin_amdgcn_mfma_f32_16x16x32_bf16(paH0, fb0, accH[nb], 0, 0, 0); \
      accH[nb] = __builtin_amdgcn_mfma_f32_16x16x32_bf16(paH1, fb1, accH[nb], 0, 0, 0); \
    }                                                                          \
  } while (0)

  // prologue: stage round 0, load round-0 adj; syncthreads drains everything
  PFLOAD(PA, 0);
  STAGE(0, 0);
  __syncthreads();

  for (int t = 0; t < NT; t += 2) {
    // even round: reads ring[0]
    PFLOAD(PB, t + 1);
    COMPUTE(PA, t);
    FENCE;
    __builtin_amdgcn_s_barrier();
    STAGE(t + 1, 1);
    MFMAPH(0);
    // odd round: reads ring[1]
    PFLOAD(PA, t + 2);
    COMPUTE(PB, t + 1);
    FENCE;
    __builtin_amdgcn_s_barrier();
    STAGE(t + 2, 0);
    MFMAPH(1);
  }

#undef PFLOAD
#undef COMPUTE
#undef STAGE
#undef FENCE
#undef MFMAPH

  float* outp = (sb == 0) ? out0 : (sb == 1) ? out1 : (sb == 2) ? out2 : out3;
  const int r0 = i0 + wm * 32 + q * 4;
#pragma unroll
  for (int nb = 0; nb < 8; nb++) {
    const int col = wn * 128 + nb * 16 + l16;
#pragma unroll
    for (int r = 0; r < 4; r++) {
      outp[(size_t)(r0 + r) * 256 + col] = accL[nb][r];
      outp[(size_t)(r0 + 16 + r) * 256 + col] = accH[nb][r];
    }
  }

  // denom: P duplicated across wn halves -> only wn==0 writes
  dsL += __shfl_xor(dsL, 16);
  dsL += __shfl_xor(dsL, 32);
  dsH += __shfl_xor(dsH, 16);
  dsH += __shfl_xor(dsH, 32);
  if (wn == 0 && lane < 16) {
    denp[sb * 8192 + i0 + wm * 32 + lane] = dsL;
    denp[sb * 8192 + i0 + wm * 32 + 16 + lane] = dsH;
  }
}

// ---------------- combine split-K partials, divide by denom, elu ----------------
__global__ __launch_bounds__(256) void k_out(float* __restrict__ out,
                                             const float* __restrict__ p1,
                                             const float* __restrict__ p2,
                                             const float* __restrict__ p3,
                                             const float* __restrict__ denp) {
  const int idx = blockIdx.x * 256 + threadIdx.x;  // grid 2048
  const int row = idx >> 6;
  float4 o = ((const float4*)out)[idx];
  float4 a = ((const float4*)p1)[idx];
  float4 b = ((const float4*)p2)[idx];
  float4 c = ((const float4*)p3)[idx];
  const float inv =
      1.0f / (denp[row] + denp[8192 + row] + denp[16384 + row] + denp[24576 + row]);
  float v0 = (o.x + a.x + b.x + c.x) * inv;
  float v1 = (o.y + a.y + b.y + c.y) * inv;
  float v2 = (o.z + a.z + b.z + c.z) * inv;
  float v3 = (o.w + a.w + b.w + c.w) * inv;
  v0 = v0 > 0.f ? v0 : expm1f(v0);
  v1 = v1 > 0.f ? v1 : expm1f(v1);
  v2 = v2 > 0.f ? v2 : expm1f(v2);
  v3 = v3 > 0.f ? v3 : expm1f(v3);
  ((float4*)out)[idx] = make_float4(v0, v1, v2, v3);
}

extern "C" void kernel_launch(void* const* d_in, const int* in_sizes, int n_in,
                              void* d_out, int out_size, void* d_ws, size_t ws_size,
                              hipStream_t stream) {
  const float* h = (const float*)d_in[0];
  const float* W = (const float*)d_in[1];
  const float* a1 = (const float*)d_in[2];
  const float* a2 = (const float*)d_in[3];
  const int* adj = (const int*)d_in[4];
  float* out = (float*)d_out;
  char* ws = (char*)d_ws;

  // ws: [whT 4MB][p1 8MB][p2 8MB][p3 8MB][denp 128K][wh1][wh2][pmax][u1][u2][gmax]
  unsigned short* whT = (unsigned short*)ws;
  float* part1 = (float*)(ws + (4u << 20));
  float* part2 = (float*)(ws + (12u << 20));
  float* part3 = (float*)(ws + (20u << 20));
  float* denp = (float*)(ws + (28u << 20));  // 4*8192
  float* wh1 = denp + 4 * 8192;
  float* wh2 = wh1 + 8192;
  float* pmax = wh2 + 8192;  // 2048
  float* u1 = pmax + 2048;
  float* u2 = u1 + 512;
  float* gmax = u2 + 512;

  hipLaunchKernelGGL(k_u, dim3(16), dim3(512), 0, stream, W, a1, a2, u1, u2);
  hipLaunchKernelGGL(k_rowvec, dim3(2048), dim3(256), 0, stream, h, u1, u2, wh1,
                     wh2, pmax);
  hipLaunchKernelGGL(k_wh, dim3(128), dim3(512), 0, stream, h, W, whT, pmax, gmax);
  hipLaunchKernelGGL(k_attn, dim3(512), dim3(256), 0, stream, adj, whT, wh1,
                     wh2, gmax, out, part1, part2, part3, denp);
  hipLaunchKernelGGL(k_out, dim3(2048), dim3(256), 0, stream, out, part1, part2,
                     part3, denp);
  (void)in_sizes; (void)n_in; (void)out_size; (void)ws_size;
}